// Round 5
// baseline (229.663 us; speedup 1.0000x reference)
//
#include <hip/hip_runtime.h>
#include <hip/hip_bf16.h>
#include <stdint.h>

#define DI __device__ __forceinline__

typedef float f32x4 __attribute__((ext_vector_type(4)));
typedef short bf16x8 __attribute__((ext_vector_type(8)));

DI uint16_t f2bf(float f) {
    union { float f; uint32_t u; } v; v.f = f;
    uint32_t r = v.u + 0x7FFF + ((v.u >> 16) & 1);
    return (uint16_t)(r >> 16);
}
DI float bf2f(uint16_t h) {
    union { uint32_t u; float f; } v; v.u = ((uint32_t)h) << 16;
    return v.f;
}
DI uint32_t pk_bf16(float x, float y) {   // RNE pack via v_cvt_pk_bf16_f32
    __hip_bfloat162 h = __float22bfloat162_rn(make_float2(x, y));
    union { __hip_bfloat162 h; uint32_t u; } v; v.h = h; return v.u;
}
// async global->LDS, 16B per lane; LDS dest = wave-uniform base + lane*16
DI void gl_lds16(const void* g, void* l) {
    __builtin_amdgcn_global_load_lds(
        (__attribute__((address_space(1))) void*)(uintptr_t)g,
        (__attribute__((address_space(3))) void*)(uintptr_t)l,
        16, 0, 0);
}

// ---------------- kernel 0: Wb transpose + WcT init (fused) ---------------
__global__ void k_prep(const float* __restrict__ Wb, uint16_t* __restrict__ WbT,
                       const float* __restrict__ Wc, uint16_t* __restrict__ WcT) {
    if (blockIdx.x == 512) {
        int tid = threadIdx.x;
        for (int idx = tid; idx < 32 * 256; idx += 256) {
            int n = idx >> 8, k = idx & 255;
            WcT[idx] = (n < 31) ? f2bf(Wc[k * 31 + n]) : (uint16_t)0;
        }
        return;
    }
    __shared__ float t[32][33];
    int kb = blockIdx.x & 63, nb = blockIdx.x >> 6;
    int tx = threadIdx.x & 31, ty0 = (threadIdx.x >> 5) * 4;
    for (int i = 0; i < 4; ++i)
        t[ty0 + i][tx] = Wb[(kb * 32 + ty0 + i) * 256 + nb * 32 + tx];
    __syncthreads();
    for (int i = 0; i < 4; ++i)
        WbT[(nb * 32 + ty0 + i) * 2048 + kb * 32 + tx] = f2bf(t[tx][ty0 + i]);
}

// ---------------- kernel 1: Y = relu([src;tar] @ Wb + bb), bf16 out -------
// m32 x n128 tile, BK=64, grid 512 (2 blocks/CU). B double-buffered in LDS
// (fragment-major: ds_read = base + lane*16, zero conflicts). A direct to
// registers with depth-1 prefetch; K-loop FULLY UNROLLED so all prefetch
// buffers have constant indices (stay in VGPRs — R4's runtime-indexed
// arrays were rematerialized, collapsing the pipeline).
__launch_bounds__(256, 2)
__global__ void k_bottleneck(const float* __restrict__ src, const float* __restrict__ tgt,
                             const uint16_t* __restrict__ WbT, const float* __restrict__ bbias,
                             uint16_t* __restrict__ Y) {
    __shared__ __align__(16) uint8_t lds[32768];   // B dbuf: 2 x 16KB
    int tid = threadIdx.x, lane = tid & 63, w = tid >> 6;
    int bm = blockIdx.x >> 1, bn = blockIdx.x & 1;  // 2 n-siblings adjacent (A dedup, as R2)
    int rowbase = bm * 32, n0 = bn * 128;
    const float* Xr = (rowbase < 4096) ? src + (size_t)rowbase * 2048
                                       : tgt + (size_t)(rowbase - 4096) * 2048;
    int rl = lane & 15, kq = lane >> 4;

    // A base: thread covers rows (rl, rl+16), k-offset kq*8 (8 fp32 = 2 float4)
    const float* Ab = Xr + (size_t)rl * 2048 + kq * 8;

    // B staging: wave w stages segs s = w*4+i; s = kb*8 + nf (kb: k32-half, nf: n16-group)
    const uint16_t* Bg[4];
    uint8_t* Bl[4];
    for (int i = 0; i < 4; ++i) {
        int s = w * 4 + i, kb = s >> 3, nf = s & 7;
        Bg[i] = WbT + (size_t)(n0 + nf * 16 + rl) * 2048 + kb * 32 + kq * 8;
        Bl[i] = lds + s * 1024;   // + buf*16384 added per call site (constant)
    }

    f32x4 acc[2][2] = {};        // [mi][nfl]
    float4 a0[2][2][2], a1[2][2][2];  // two prefetch sets: [mi][kb][half]

    // prologue: stage B(t=0) into buf0, load A(t=0) into set0
    for (int i = 0; i < 4; ++i) gl_lds16(Bg[i], Bl[i]);
#pragma unroll
    for (int mi = 0; mi < 2; ++mi)
#pragma unroll
        for (int kb = 0; kb < 2; ++kb) {
            const float* p = Ab + (size_t)mi * 16 * 2048 + kb * 32;
            a0[mi][kb][0] = *(const float4*)(p);
            a0[mi][kb][1] = *(const float4*)(p + 4);
        }
    __syncthreads();   // drains vmcnt(0): buf0 + A set0 ready

#pragma unroll
    for (int t = 0; t < 32; ++t) {
        const int cur = t & 1;
        // issue next-iteration A loads (HBM, longest latency) and B staging first
        if (t < 31) {
            int k0n = (t + 1) * 64;
#pragma unroll
            for (int mi = 0; mi < 2; ++mi)
#pragma unroll
                for (int kb = 0; kb < 2; ++kb) {
                    const float* p = Ab + (size_t)mi * 16 * 2048 + kb * 32 + k0n;
                    if (cur == 0) {
                        a1[mi][kb][0] = *(const float4*)(p);
                        a1[mi][kb][1] = *(const float4*)(p + 4);
                    } else {
                        a0[mi][kb][0] = *(const float4*)(p);
                        a0[mi][kb][1] = *(const float4*)(p + 4);
                    }
                }
            for (int i = 0; i < 4; ++i)
                gl_lds16(Bg[i] + k0n, Bl[i] + (cur ^ 1) * 16384);
        }
        // pack current A set (complete since last barrier)
        union { uint4 u; bf16x8 v; } af[2][2];
#pragma unroll
        for (int mi = 0; mi < 2; ++mi)
#pragma unroll
            for (int kb = 0; kb < 2; ++kb) {
                float4 x0 = (cur == 0) ? a0[mi][kb][0] : a1[mi][kb][0];
                float4 x1 = (cur == 0) ? a0[mi][kb][1] : a1[mi][kb][1];
                af[mi][kb].u.x = pk_bf16(x0.x, x0.y);
                af[mi][kb].u.y = pk_bf16(x0.z, x0.w);
                af[mi][kb].u.z = pk_bf16(x1.x, x1.y);
                af[mi][kb].u.w = pk_bf16(x1.z, x1.w);
            }
        // compute from buf[cur]: 4 ds_read_b128 + 8 MFMA per wave
#pragma unroll
        for (int kb = 0; kb < 2; ++kb)
#pragma unroll
            for (int nfl = 0; nfl < 2; ++nfl) {
                bf16x8 b = *(const bf16x8*)(lds + cur * 16384 +
                                            (kb * 8 + w * 2 + nfl) * 1024 + lane * 16);
                acc[0][nfl] = __builtin_amdgcn_mfma_f32_16x16x32_bf16(
                    af[0][kb].v, b, acc[0][nfl], 0, 0, 0);
                acc[1][nfl] = __builtin_amdgcn_mfma_f32_16x16x32_bf16(
                    af[1][kb].v, b, acc[1][nfl], 0, 0, 0);
            }
        __syncthreads();  // drain t+1 staging (covered by this iter's compute); WAR on buf
    }

    for (int mi = 0; mi < 2; ++mi)
        for (int nfl = 0; nfl < 2; ++nfl) {
            int col = n0 + w * 32 + nfl * 16 + rl;
            float bias = bbias[col];
            for (int j = 0; j < 4; ++j) {
                int row = rowbase + mi * 16 + kq * 4 + j;
                float v = fmaxf(acc[mi][nfl][j] + bias, 0.f);
                Y[(size_t)row * 256 + col] = f2bf(v);
            }
        }
}

// ---------------- kernel 2: fused row sum-of-squares + column partials ---
__global__ void k_stats(const uint16_t* __restrict__ Y, float* __restrict__ s2t2,
                        float* __restrict__ part) {
    __shared__ float sred[4][256];
    int tid = threadIdx.x, cg = tid & 63, rs = tid >> 6;
    int r0 = blockIdx.x * 16;
    float a0 = 0.f, a1 = 0.f, a2 = 0.f, a3 = 0.f;
    for (int it = 0; it < 4; ++it) {
        int row = r0 + it * 4 + rs;
        ushort4 v = *(const ushort4*)(Y + (size_t)row * 256 + cg * 4);
        float f0 = bf2f(v.x), f1 = bf2f(v.y), f2 = bf2f(v.z), f3 = bf2f(v.w);
        a0 += f0; a1 += f1; a2 += f2; a3 += f3;
        float s = f0 * f0 + f1 * f1 + f2 * f2 + f3 * f3;
        for (int m = 1; m < 64; m <<= 1) s += __shfl_xor(s, m);
        if (cg == 0) s2t2[row] = s;
    }
    sred[rs][cg * 4 + 0] = a0; sred[rs][cg * 4 + 1] = a1;
    sred[rs][cg * 4 + 2] = a2; sred[rs][cg * 4 + 3] = a3;
    __syncthreads();
    if (rs == 0)
        for (int i = 0; i < 4; ++i) {
            int col = cg * 4 + i;
            part[blockIdx.x * 256 + col] =
                sred[0][col] + sred[1][col] + sred[2][col] + sred[3][col];
        }
}

// ---------------- kernel 3: classifier (wave-level, barrier-free) --------
__launch_bounds__(64)
__global__ void k_classifier(const uint16_t* __restrict__ Y, const uint16_t* __restrict__ WcT,
                             const float* __restrict__ bc, const int* __restrict__ labels,
                             float* __restrict__ out_margin, float* __restrict__ ce_part) {
    int lane = threadIdx.x;
    int r0 = blockIdx.x * 16;
    bool is_src = (r0 < 4096);
    int rl = lane & 15, kq = lane >> 4;
    const uint16_t* Ap = Y + (size_t)(r0 + rl) * 256 + kq * 8;
    const uint16_t* Bp = WcT + (size_t)rl * 256 + kq * 8;
    f32x4 acc[2] = {};
#pragma unroll
    for (int kb = 0; kb < 8; ++kb) {
        bf16x8 a  = *(const bf16x8*)(Ap + kb * 32);
        bf16x8 b0 = *(const bf16x8*)(Bp + kb * 32);
        bf16x8 b1 = *(const bf16x8*)(Bp + 16 * 256 + kb * 32);
        acc[0] = __builtin_amdgcn_mfma_f32_16x16x32_bf16(a, b0, acc[0], 0, 0, 0);
        acc[1] = __builtin_amdgcn_mfma_f32_16x16x32_bf16(a, b1, acc[1], 0, 0, 0);
    }
    int c0 = rl, c1 = 16 + rl;
    float bc0 = bc[c0];
    float bc1 = (c1 < 31) ? bc[c1] : 0.f;
    float ce_local = 0.f;
    for (int j = 0; j < 4; ++j) {
        int row = r0 + kq * 4 + j;
        float v0 = acc[0][j] + bc0;
        float v1 = (c1 < 31) ? (acc[1][j] + bc1) : -1e30f;
        float mx = fmaxf(v0, v1);
        for (int m = 1; m < 16; m <<= 1) mx = fmaxf(mx, __shfl_xor(mx, m, 16));
        float e0 = __expf(v0 - mx);
        float e1 = (c1 < 31) ? __expf(v1 - mx) : 0.f;
        float ssum = e0 + e1;
        for (int m = 1; m < 16; m <<= 1) ssum += __shfl_xor(ssum, m, 16);
        float inv = 1.f / ssum;
        float conf0 = e0 * inv, conf1 = e1 * inv;
        int lab;
        if (is_src) {
            lab = labels[row];
        } else {
            float bv; int bi;
            if (v0 >= v1) { bv = v0; bi = c0; } else { bv = v1; bi = c1; }
            for (int m = 1; m < 16; m <<= 1) {
                float ov = __shfl_xor(bv, m, 16);
                int oi = __shfl_xor(bi, m, 16);
                if (ov > bv || (ov == bv && oi < bi)) { bv = ov; bi = oi; }
            }
            lab = bi;
        }
        float tc = (c0 == lab ? conf0 : 0.f) + (c1 == lab ? conf1 : 0.f);
        for (int m = 1; m < 16; m <<= 1) tc += __shfl_xor(tc, m, 16);
        float ex = fmaxf(c0 == lab ? -1.f : conf0,
                         (c1 == lab || c1 >= 31) ? -1.f : conf1);
        for (int m = 1; m < 16; m <<= 1) ex = fmaxf(ex, __shfl_xor(ex, m, 16));
        if (c0 == 0) out_margin[row] = tc - ex;
        if (is_src) {
            float vl = (c0 == lab) ? v0 : ((c1 == lab) ? v1 : -1e30f);
            for (int m = 1; m < 16; m <<= 1) vl = fmaxf(vl, __shfl_xor(vl, m, 16));
            if (c0 == 0) ce_local += -(vl - mx - __logf(ssum));
        }
    }
    ce_local += __shfl_xor(ce_local, 16);
    ce_local += __shfl_xor(ce_local, 32);
    if (lane == 0) ce_part[blockIdx.x] = is_src ? ce_local : 0.f;
}

// ---------------- kernel 4: pairwise d2 -> exp partial sums -------------
__launch_bounds__(256)
__global__ void k_pairwise(const uint16_t* __restrict__ Y, const float* __restrict__ s2t2,
                           float* __restrict__ gk_part) {
    __shared__ __align__(16) uint8_t lds[32768];  // A 16KB @0, B 16KB @16384
    int tid = threadIdx.x, lane = tid & 63, w = tid >> 6;
    int m0 = blockIdx.x * 128, n0 = blockIdx.y * 128;
    int cc = (lane >> 4) ^ (lane & 3) ^ ((lane >> 2) & 3);
    int wm = (w & 1) * 64, wn = (w >> 1) * 64;
    f32x4 acc[4][4] = {};
    for (int h = 0; h < 4; ++h) {
        if (h) __syncthreads();
        int k0 = h * 64;
        for (int i = 0; i < 4; ++i) {
            int s = w * 4 + i;
            int kb = s >> 3, r0 = (s & 7) * 16;
            int r = r0 + (lane >> 2), p = lane & 3;
            int c = p ^ (r & 3) ^ ((r >> 2) & 3);
            gl_lds16(Y + (size_t)(m0 + r) * 256 + k0 + kb * 32 + c * 8, lds + s * 1024);
            gl_lds16(Y + (size_t)(4096 + n0 + r) * 256 + k0 + kb * 32 + c * 8,
                     lds + 16384 + s * 1024);
        }
        __syncthreads();
        for (int kb = 0; kb < 2; ++kb) {
            bf16x8 a[4], b[4];
            for (int mi = 0; mi < 4; ++mi) {
                int r = wm + mi * 16 + (lane & 15);
                a[mi] = *(const bf16x8*)(lds + kb * 8192 + r * 64 + cc * 16);
            }
            for (int nf = 0; nf < 4; ++nf) {
                int rn = wn + nf * 16 + (lane & 15);
                b[nf] = *(const bf16x8*)(lds + 16384 + kb * 8192 + rn * 64 + cc * 16);
            }
            for (int mi = 0; mi < 4; ++mi)
                for (int nf = 0; nf < 4; ++nf)
                    acc[mi][nf] = __builtin_amdgcn_mfma_f32_16x16x32_bf16(
                        a[mi], b[nf], acc[mi][nf], 0, 0, 0);
        }
    }
    float t2v[4];
    for (int nf = 0; nf < 4; ++nf)
        t2v[nf] = s2t2[4096 + n0 + wn + nf * 16 + (lane & 15)];
    float g1 = 0.f, g5 = 0.f;
    for (int mi = 0; mi < 4; ++mi) {
        int rbase = m0 + wm + mi * 16 + (lane >> 4) * 4;
        float s2v[4];
        for (int j = 0; j < 4; ++j) s2v[j] = s2t2[rbase + j];
        for (int nf = 0; nf < 4; ++nf)
            for (int j = 0; j < 4; ++j) {
                float d2 = s2v[j] + t2v[nf] - 2.f * acc[mi][nf][j];
                d2 = fmaxf(d2, 0.f);
                g1 += __expf(-0.5f * d2);
                g5 += __expf(-0.02f * d2);
            }
    }
    for (int m = 1; m < 64; m <<= 1) { g1 += __shfl_xor(g1, m); g5 += __shfl_xor(g5, m); }
    __syncthreads();
    float* red = (float*)lds;
    if (lane == 0) { red[w * 2] = g1; red[w * 2 + 1] = g5; }
    __syncthreads();
    if (tid == 0) {
        int bid = blockIdx.y * 32 + blockIdx.x;
        gk_part[bid * 2]     = red[0] + red[2] + red[4] + red[6];
        gk_part[bid * 2 + 1] = red[1] + red[3] + red[5] + red[7];
    }
}

// ---------------- kernel 5: finalize scalars ----------------------------
__global__ void k_finalize(const float* __restrict__ colsum_part,
                           const float* __restrict__ gk_part,
                           const float* __restrict__ ce_part, float* __restrict__ d_out) {
    __shared__ float red[4][4];
    int tid = threadIdx.x, lane = tid & 63, w = tid >> 6;
    float cs = 0.f, ct = 0.f;
#pragma unroll 8
    for (int b = 0; b < 256; ++b)   cs += colsum_part[b * 256 + tid];
#pragma unroll 8
    for (int b = 256; b < 512; ++b) ct += colsum_part[b * 256 + tid];
    float delta = (cs - ct) * (1.f / 4096.f);
    float sq = delta * delta;
    float g1 = 0.f, g5 = 0.f;
    for (int i = 0; i < 4; ++i) {
        int p = tid * 4 + i;
        g1 += gk_part[p * 2];
        g5 += gk_part[p * 2 + 1];
    }
    float ce = ce_part[tid] + ce_part[tid + 256];
    for (int m = 1; m < 64; m <<= 1) {
        sq += __shfl_xor(sq, m);
        g1 += __shfl_xor(g1, m);
        g5 += __shfl_xor(g5, m);
        ce += __shfl_xor(ce, m);
    }
    if (lane == 0) { red[w][0] = sq; red[w][1] = g1; red[w][2] = g5; red[w][3] = ce; }
    __syncthreads();
    if (tid == 0) {
        d_out[0] = (red[0][3] + red[1][3] + red[2][3] + red[3][3]) * (1.f / 4096.f);
        d_out[1] = red[0][0] + red[1][0] + red[2][0] + red[3][0];
        d_out[2] = (red[0][1] + red[1][1] + red[2][1] + red[3][1]) * 5.9604644775390625e-08f;
        d_out[3] = (red[0][2] + red[1][2] + red[2][2] + red[3][2]) * 5.9604644775390625e-08f;
    }
}

extern "C" void kernel_launch(void* const* d_in, const int* in_sizes, int n_in,
                              void* d_out, int out_size, void* d_ws, size_t ws_size,
                              hipStream_t stream) {
    const float* source = (const float*)d_in[0];
    const float* target = (const float*)d_in[1];
    const float* Wb     = (const float*)d_in[2];
    const float* bb     = (const float*)d_in[3];
    const float* Wc     = (const float*)d_in[4];
    const float* bc     = (const float*)d_in[5];
    const int*   labels = (const int*)d_in[6];
    float* out = (float*)d_out;
    uint8_t* ws = (uint8_t*)d_ws;

    uint16_t* Y    = (uint16_t*)(ws);                 // 4 MB
    uint16_t* WbT  = (uint16_t*)(ws + 4194304);       // 1 MB (dead after k_bottleneck)
    uint16_t* WcT  = (uint16_t*)(ws + 5242880);       // 16 KB
    float*    s2t2 = (float*)(ws + 5259264);          // 32 KB
    // alias dead WbT region (WbT only read by k_bottleneck, which runs first):
    float* colsum_part = (float*)(ws + 4194304);            // 512*256*4 = 512 KB
    float* gk_part     = (float*)(ws + 4194304 + 524288);   // 1024*2*4 = 8 KB
    float* ce_part     = (float*)(ws + 4194304 + 532480);   // 512*4 = 2 KB

    k_prep<<<513, 256, 0, stream>>>(Wb, WbT, Wc, WcT);
    k_bottleneck<<<512, 256, 0, stream>>>(source, target, WbT, bb, Y);
    k_stats<<<512, 256, 0, stream>>>(Y, s2t2, colsum_part);
    k_classifier<<<512, 64, 0, stream>>>(Y, WcT, bc, labels, out + 4, ce_part);
    k_pairwise<<<dim3(32, 32), 256, 0, stream>>>(Y, s2t2, gk_part);
    k_finalize<<<1, 256, 0, stream>>>(colsum_part, gk_part, ce_part, out);
}

// Round 6
// 216.259 us; speedup vs baseline: 1.0620x; 1.0620x over previous
//
#include <hip/hip_runtime.h>
#include <hip/hip_bf16.h>
#include <stdint.h>

#define DI __device__ __forceinline__

typedef float f32x4 __attribute__((ext_vector_type(4)));
typedef short bf16x8 __attribute__((ext_vector_type(8)));

DI uint16_t f2bf(float f) {
    union { float f; uint32_t u; } v; v.f = f;
    uint32_t r = v.u + 0x7FFF + ((v.u >> 16) & 1);
    return (uint16_t)(r >> 16);
}
DI float bf2f(uint16_t h) {
    union { uint32_t u; float f; } v; v.u = ((uint32_t)h) << 16;
    return v.f;
}
DI uint32_t pk_bf16(float x, float y) {
    __hip_bfloat162 h = __float22bfloat162_rn(make_float2(x, y));
    union { __hip_bfloat162 h; uint32_t u; } v; v.h = h; return v.u;
}
DI void gl_lds16(const void* g, void* l) {
    __builtin_amdgcn_global_load_lds(
        (__attribute__((address_space(1))) void*)(uintptr_t)g,
        (__attribute__((address_space(3))) void*)(uintptr_t)l,
        16, 0, 0);
}

// Fragment conventions (16x16x32 MFMA):
//  Yf (standard k-order): frag(mb = row>>4, c = col>>5): lane = (row&15) + ((col>>3)&3)*16,
//    halfword i = col&7. 1 KB per frag, dense.
//  Bf (Wb, PERMUTED k to match dense fp32 A-loads): lane (rl,kq) holds
//    k = {kq*4..kq*4+3, 16+kq*4..16+kq*4+3} of its 32-chunk, n = nf*16+rl.
//  Wcf (classifier weights, standard k-order).

// ---------------- kernel 0: prep — Bf (64 blocks) + Wcf (block 64) --------
__global__ void k_prep(const float* __restrict__ Wb, uint16_t* __restrict__ Bf,
                       const float* __restrict__ Wc, uint16_t* __restrict__ Wcf) {
    __shared__ float wlds[8192];   // 32 KB
    int tid = threadIdx.x;
    if (blockIdx.x < 64) {
        int c = blockIdx.x;
        for (int r = 0; r < 32; ++r)
            wlds[r * 256 + tid] = Wb[(size_t)(c * 32 + r) * 256 + tid];
        __syncthreads();
        for (int e = tid; e < 1024; e += 256) {
            int nf = e >> 6, ln = e & 63, erl = ln & 15, ekq = ln >> 4;
            ushort o[8];
            for (int i = 0; i < 8; ++i) {
                int kl = (i < 4) ? (ekq * 4 + i) : (16 + ekq * 4 + (i - 4));
                o[i] = f2bf(wlds[kl * 256 + nf * 16 + erl]);
            }
            *(uint4*)(Bf + ((size_t)c * 16 + nf) * 512 + ln * 8) = *(uint4*)o;
        }
    } else {
        for (int idx = tid; idx < 256 * 31; idx += 256) wlds[idx] = Wc[idx];
        __syncthreads();
        for (int e = tid; e < 1024; e += 256) {
            int kb = e >> 7, rest = e & 127, nf = rest >> 6, ln = rest & 63;
            int erl = ln & 15, ekq = ln >> 4;
            ushort o[8];
            for (int i = 0; i < 8; ++i) {
                int k = kb * 32 + ekq * 8 + i, n = nf * 16 + erl;
                o[i] = (n < 31) ? f2bf(wlds[k * 31 + n]) : (ushort)0;
            }
            *(uint4*)(Wcf + ((size_t)(kb * 2 + nf)) * 512 + ln * 8) = *(uint4*)o;
        }
    }
}

// ---------------- kernel 1: Yf = relu([src;tar] @ Wb + bb) ---------------
// wave m32 x n64, block = 4 waves (m128 x n64), grid 256 = 1 block/CU.
// ZERO barriers, ZERO LDS. All global loads are per-wave line-dense:
//   A: permuted-k fragment loads (each float4-instr = 16 rows x one 64B line)
//   B: pre-fragmented, one contiguous 1KB dwordx4 per frag.
__launch_bounds__(256, 1)
__global__ void k_bottleneck(const float* __restrict__ src, const float* __restrict__ tgt,
                             const uint16_t* __restrict__ Bf, const float* __restrict__ bbias,
                             uint16_t* __restrict__ Yf) {
    int tid = threadIdx.x, lane = tid & 63, w = tid >> 6;
    int bm = blockIdx.x >> 2, bn = blockIdx.x & 3;
    int rowbase = bm * 128 + w * 32;
    const float* Xr = (rowbase < 4096) ? src + (size_t)rowbase * 2048
                                       : tgt + (size_t)(rowbase - 4096) * 2048;
    int rl = lane & 15, kq = lane >> 4;
    const float* A0 = Xr + (size_t)rl * 2048 + kq * 4;
    const float* A1 = Xr + (size_t)(16 + rl) * 2048 + kq * 4;
    const uint16_t* Bp = Bf + (size_t)(bn * 4) * 512 + lane * 8;

    f32x4 acc[2][4] = {};
#pragma unroll
    for (int c = 0; c < 64; ++c) {
        int k0 = c * 32;
        float4 x00 = *(const float4*)(A0 + k0);
        float4 x01 = *(const float4*)(A0 + k0 + 16);
        float4 x10 = *(const float4*)(A1 + k0);
        float4 x11 = *(const float4*)(A1 + k0 + 16);
        bf16x8 b[4];
#pragma unroll
        for (int nf = 0; nf < 4; ++nf)
            b[nf] = *(const bf16x8*)(Bp + ((size_t)c * 16 + nf) * 512);
        union { uint4 u; bf16x8 v; } a0, a1;
        a0.u.x = pk_bf16(x00.x, x00.y); a0.u.y = pk_bf16(x00.z, x00.w);
        a0.u.z = pk_bf16(x01.x, x01.y); a0.u.w = pk_bf16(x01.z, x01.w);
        a1.u.x = pk_bf16(x10.x, x10.y); a1.u.y = pk_bf16(x10.z, x10.w);
        a1.u.z = pk_bf16(x11.x, x11.y); a1.u.w = pk_bf16(x11.z, x11.w);
#pragma unroll
        for (int nf = 0; nf < 4; ++nf) {
            acc[0][nf] = __builtin_amdgcn_mfma_f32_16x16x32_bf16(a0.v, b[nf], acc[0][nf], 0, 0, 0);
            acc[1][nf] = __builtin_amdgcn_mfma_f32_16x16x32_bf16(a1.v, b[nf], acc[1][nf], 0, 0, 0);
        }
    }
    // epilogue: bias+relu, store into fragment-major Yf (2B scattered, fire-and-forget)
    for (int nf = 0; nf < 4; ++nf) {
        int col = bn * 64 + nf * 16 + rl;
        float bias = bbias[col];
        for (int mi = 0; mi < 2; ++mi) {
            size_t fi = (size_t)((bm * 8 + w * 2 + mi) * 8 + bn * 2 + (nf >> 1));
            for (int j = 0; j < 4; ++j) {
                float v = fmaxf(acc[mi][nf][j] + bias, 0.f);
                int ln = (kq * 4 + j) + ((nf & 1) * 2 + (rl >> 3)) * 16;
                Yf[fi * 512 + ln * 8 + (rl & 7)] = f2bf(v);
            }
        }
    }
}

// ---------------- kernel 2: fused row s2 + column partial sums (from Yf) --
__global__ void k_stats(const uint16_t* __restrict__ Yf, float* __restrict__ s2t2,
                        float* __restrict__ part) {
    __shared__ float rowred[8][16];
    int tid = threadIdx.x, lane = tid & 63, w = tid >> 6;
    int mb = blockIdx.x;
    int rl = lane & 15, kq = lane >> 4;
    for (int ci = 0; ci < 2; ++ci) {
        int c = w * 2 + ci;
        bf16x8 vv = *(const bf16x8*)(Yf + ((size_t)mb * 8 + c) * 512 + lane * 8);
        union { bf16x8 v; ushort s[8]; } u; u.v = vv;
        float f[8], s2 = 0.f;
        for (int i = 0; i < 8; ++i) { f[i] = bf2f(u.s[i]); s2 += f[i] * f[i]; }
        s2 += __shfl_xor(s2, 16); s2 += __shfl_xor(s2, 32);
        if (kq == 0) rowred[c][rl] = s2;
        for (int m = 1; m < 16; m <<= 1)
            for (int i = 0; i < 8; ++i) f[i] += __shfl_xor(f[i], m);
        if (rl == 0)
            for (int i = 0; i < 8; ++i)
                part[(size_t)mb * 256 + c * 32 + kq * 8 + i] = f[i];
    }
    __syncthreads();
    if (tid < 16) {
        float s = 0.f;
        for (int c = 0; c < 8; ++c) s += rowred[c][tid];
        s2t2[mb * 16 + tid] = s;
    }
}

// ---------------- kernel 3: classifier (wave-level, dense frag reads) ----
__launch_bounds__(64)
__global__ void k_classifier(const uint16_t* __restrict__ Yf, const uint16_t* __restrict__ Wcf,
                             const float* __restrict__ bc, const int* __restrict__ labels,
                             float* __restrict__ out_margin, float* __restrict__ ce_part) {
    int lane = threadIdx.x;
    int mb = blockIdx.x, r0 = mb * 16;
    bool is_src = (r0 < 4096);
    int rl = lane & 15, kq = lane >> 4;
    f32x4 acc[2] = {};
#pragma unroll
    for (int kb = 0; kb < 8; ++kb) {
        bf16x8 a  = *(const bf16x8*)(Yf + ((size_t)mb * 8 + kb) * 512 + lane * 8);
        bf16x8 b0 = *(const bf16x8*)(Wcf + ((size_t)(kb * 2 + 0)) * 512 + lane * 8);
        bf16x8 b1 = *(const bf16x8*)(Wcf + ((size_t)(kb * 2 + 1)) * 512 + lane * 8);
        acc[0] = __builtin_amdgcn_mfma_f32_16x16x32_bf16(a, b0, acc[0], 0, 0, 0);
        acc[1] = __builtin_amdgcn_mfma_f32_16x16x32_bf16(a, b1, acc[1], 0, 0, 0);
    }
    int c0 = rl, c1 = 16 + rl;
    float bc0 = bc[c0];
    float bc1 = (c1 < 31) ? bc[c1] : 0.f;
    float ce_local = 0.f;
    for (int j = 0; j < 4; ++j) {
        int row = r0 + kq * 4 + j;
        float v0 = acc[0][j] + bc0;
        float v1 = (c1 < 31) ? (acc[1][j] + bc1) : -1e30f;
        float mx = fmaxf(v0, v1);
        for (int m = 1; m < 16; m <<= 1) mx = fmaxf(mx, __shfl_xor(mx, m, 16));
        float e0 = __expf(v0 - mx);
        float e1 = (c1 < 31) ? __expf(v1 - mx) : 0.f;
        float ssum = e0 + e1;
        for (int m = 1; m < 16; m <<= 1) ssum += __shfl_xor(ssum, m, 16);
        float inv = 1.f / ssum;
        float conf0 = e0 * inv, conf1 = e1 * inv;
        int lab;
        if (is_src) {
            lab = labels[row];
        } else {
            float bv; int bi;
            if (v0 >= v1) { bv = v0; bi = c0; } else { bv = v1; bi = c1; }
            for (int m = 1; m < 16; m <<= 1) {
                float ov = __shfl_xor(bv, m, 16);
                int oi = __shfl_xor(bi, m, 16);
                if (ov > bv || (ov == bv && oi < bi)) { bv = ov; bi = oi; }
            }
            lab = bi;
        }
        float tc = (c0 == lab ? conf0 : 0.f) + (c1 == lab ? conf1 : 0.f);
        for (int m = 1; m < 16; m <<= 1) tc += __shfl_xor(tc, m, 16);
        float ex = fmaxf(c0 == lab ? -1.f : conf0,
                         (c1 == lab || c1 >= 31) ? -1.f : conf1);
        for (int m = 1; m < 16; m <<= 1) ex = fmaxf(ex, __shfl_xor(ex, m, 16));
        if (c0 == 0) out_margin[row] = tc - ex;
        if (is_src) {
            float vl = (c0 == lab) ? v0 : ((c1 == lab) ? v1 : -1e30f);
            for (int m = 1; m < 16; m <<= 1) vl = fmaxf(vl, __shfl_xor(vl, m, 16));
            if (c0 == 0) ce_local += -(vl - mx - __logf(ssum));
        }
    }
    ce_local += __shfl_xor(ce_local, 16);
    ce_local += __shfl_xor(ce_local, 32);
    if (lane == 0) ce_part[blockIdx.x] = is_src ? ce_local : 0.f;
}

// ---------------- kernel 4: pairwise d2 -> exp partial sums --------------
// 128x128 tile, K=256 in 4 phases; dense 1KB-frag gl_lds16 staging.
__launch_bounds__(256)
__global__ void k_pairwise(const uint16_t* __restrict__ Yf, const float* __restrict__ s2t2,
                           float* __restrict__ gk_part) {
    __shared__ __align__(16) uint8_t lds[32768];  // A 16KB @0, B 16KB @16384
    int tid = threadIdx.x, lane = tid & 63, w = tid >> 6;
    int m0 = blockIdx.x * 128, n0 = blockIdx.y * 128;
    int wm = (w & 1) * 64, wn = (w >> 1) * 64;
    f32x4 acc[4][4] = {};
    for (int h = 0; h < 4; ++h) {
        if (h) __syncthreads();
        for (int i = 0; i < 8; ++i) {
            int s = w * 8 + i;                 // 0..31
            int t = s & 15, mbi = t >> 1, ci = t & 1;
            size_t fi = (s < 16)
                ? ((size_t)(m0 / 16 + mbi) * 8 + 2 * h + ci)
                : ((size_t)(256 + n0 / 16 + mbi) * 8 + 2 * h + ci);
            gl_lds16(Yf + fi * 512 + lane * 8,
                     lds + ((s < 16) ? 0 : 16384) + t * 1024 + lane * 16);
        }
        __syncthreads();
        for (int kb = 0; kb < 2; ++kb) {
            bf16x8 a[4], b[4];
            for (int mi = 0; mi < 4; ++mi)
                a[mi] = *(const bf16x8*)(lds + (((w & 1) * 4 + mi) * 2 + kb) * 1024 + lane * 16);
            for (int nf = 0; nf < 4; ++nf)
                b[nf] = *(const bf16x8*)(lds + 16384 + (((w >> 1) * 4 + nf) * 2 + kb) * 1024 + lane * 16);
            for (int mi = 0; mi < 4; ++mi)
                for (int nf = 0; nf < 4; ++nf)
                    acc[mi][nf] = __builtin_amdgcn_mfma_f32_16x16x32_bf16(
                        a[mi], b[nf], acc[mi][nf], 0, 0, 0);
        }
    }
    float t2v[4];
    for (int nf = 0; nf < 4; ++nf)
        t2v[nf] = s2t2[4096 + n0 + wn + nf * 16 + (lane & 15)];
    float g1 = 0.f, g5 = 0.f;
    for (int mi = 0; mi < 4; ++mi) {
        int rbase = m0 + wm + mi * 16 + (lane >> 4) * 4;
        float s2v[4];
        for (int j = 0; j < 4; ++j) s2v[j] = s2t2[rbase + j];
        for (int nf = 0; nf < 4; ++nf)
            for (int j = 0; j < 4; ++j) {
                float d2 = s2v[j] + t2v[nf] - 2.f * acc[mi][nf][j];
                d2 = fmaxf(d2, 0.f);
                g1 += __expf(-0.5f * d2);
                g5 += __expf(-0.02f * d2);
            }
    }
    for (int m = 1; m < 64; m <<= 1) { g1 += __shfl_xor(g1, m); g5 += __shfl_xor(g5, m); }
    __syncthreads();
    float* red = (float*)lds;
    if (lane == 0) { red[w * 2] = g1; red[w * 2 + 1] = g5; }
    __syncthreads();
    if (tid == 0) {
        int bid = blockIdx.y * 32 + blockIdx.x;
        gk_part[bid * 2]     = red[0] + red[2] + red[4] + red[6];
        gk_part[bid * 2 + 1] = red[1] + red[3] + red[5] + red[7];
    }
}

// ---------------- kernel 5: finalize scalars ----------------------------
__global__ void k_finalize(const float* __restrict__ colsum_part,
                           const float* __restrict__ gk_part,
                           const float* __restrict__ ce_part, float* __restrict__ d_out) {
    __shared__ float red[4][4];
    int tid = threadIdx.x, lane = tid & 63, w = tid >> 6;
    float cs = 0.f, ct = 0.f;
#pragma unroll 8
    for (int b = 0; b < 256; ++b)   cs += colsum_part[(size_t)b * 256 + tid];
#pragma unroll 8
    for (int b = 256; b < 512; ++b) ct += colsum_part[(size_t)b * 256 + tid];
    float delta = (cs - ct) * (1.f / 4096.f);
    float sq = delta * delta;
    float g1 = 0.f, g5 = 0.f;
    for (int i = 0; i < 4; ++i) {
        int p = tid * 4 + i;
        g1 += gk_part[p * 2];
        g5 += gk_part[p * 2 + 1];
    }
    float ce = ce_part[tid] + ce_part[tid + 256];
    for (int m = 1; m < 64; m <<= 1) {
        sq += __shfl_xor(sq, m);
        g1 += __shfl_xor(g1, m);
        g5 += __shfl_xor(g5, m);
        ce += __shfl_xor(ce, m);
    }
    if (lane == 0) { red[w][0] = sq; red[w][1] = g1; red[w][2] = g5; red[w][3] = ce; }
    __syncthreads();
    if (tid == 0) {
        d_out[0] = (red[0][3] + red[1][3] + red[2][3] + red[3][3]) * (1.f / 4096.f);
        d_out[1] = red[0][0] + red[1][0] + red[2][0] + red[3][0];
        d_out[2] = (red[0][1] + red[1][1] + red[2][1] + red[3][1]) * 5.9604644775390625e-08f;
        d_out[3] = (red[0][2] + red[1][2] + red[2][2] + red[3][2]) * 5.9604644775390625e-08f;
    }
}

extern "C" void kernel_launch(void* const* d_in, const int* in_sizes, int n_in,
                              void* d_out, int out_size, void* d_ws, size_t ws_size,
                              hipStream_t stream) {
    const float* source = (const float*)d_in[0];
    const float* target = (const float*)d_in[1];
    const float* Wb     = (const float*)d_in[2];
    const float* bb     = (const float*)d_in[3];
    const float* Wc     = (const float*)d_in[4];
    const float* bc     = (const float*)d_in[5];
    const int*   labels = (const int*)d_in[6];
    float* out = (float*)d_out;
    uint8_t* ws = (uint8_t*)d_ws;

    uint16_t* Yf   = (uint16_t*)(ws);                 // 4 MB, fragment-major
    uint16_t* Bf   = (uint16_t*)(ws + 4194304);       // 1 MB (dead after k_bottleneck)
    uint16_t* Wcf  = (uint16_t*)(ws + 5242880);       // 16 KB
    float*    s2t2 = (float*)(ws + 5259264);          // 32 KB
    // alias dead Bf region (only read by k_bottleneck, which runs first):
    float* colsum_part = (float*)(ws + 4194304);            // 512*256*4 = 512 KB
    float* gk_part     = (float*)(ws + 4194304 + 524288);   // 8 KB
    float* ce_part     = (float*)(ws + 4194304 + 532480);   // 2 KB

    k_prep<<<65, 256, 0, stream>>>(Wb, Bf, Wc, Wcf);
    k_bottleneck<<<256, 256, 0, stream>>>(source, target, Bf, bb, Yf);
    k_stats<<<512, 256, 0, stream>>>(Yf, s2t2, colsum_part);
    k_classifier<<<512, 64, 0, stream>>>(Yf, Wcf, bc, labels, out + 4, ce_part);
    k_pairwise<<<dim3(32, 32), 256, 0, stream>>>(Yf, s2t2, gk_part);
    k_finalize<<<1, 256, 0, stream>>>(colsum_part, gk_part, ce_part, out);
}